// Round 9
// baseline (289.305 us; speedup 1.0000x reference)
//
#include <hip/hip_runtime.h>
#include <hip/hip_fp16.h>
#include <math.h>
#include <type_traits>

// ----------------------------------------------------------------------------
// NL-means denoise (skimage slow-mode math) + db2-wavelet sigma estimate.
// Stage 1: wavelet HH conv (stride-2 SAMPLED grid, 257x257/channel) -> hist
// Stage 2: single-block shfl-scan -> per-channel median -> sigma
// Stage 3: tiled NLM, offset pairs packed as half2 (R6).
// R9: WAVE-AUTONOMOUS tiles — each wave owns a 16x16 output tile with
//     wave-private sdh (20x20 diff^2) and shh slices; spx block-shared but
//     read-only after ONE init barrier. Zero __syncthreads in the 90-pair
//     loop (all phase deps are same-wave LDS RAW, in-order per ISA).
//     R8 post-mortem: 2 barriers/pair x 84 pairs left ~60us (28%) neither-
//     pipe stall at VALU 72% / LDS ~70%; read-merge didn't help because the
//     LDS pipe is data-limited, not issue-limited. Cost: +17% phase-A work
//     (ext overlap). Bank audit: stride-20 rows -> 2-way (free) patterns.
// ----------------------------------------------------------------------------

#define IMG   1024
#define HH_S  257        // sampled HH grid per side (every 2nd of 514)
#define NBINS 4096
#define NREP  2
#define BIN_SCALE 4096.0f
#define MED_K 33025      // n=257*257=66049 odd: median = a[33024] (0-based)

#define TW 64            // block tile = 4 wave-tiles of 16 wide
#define TH 16
#define WTS 16           // wave tile 16x16
#define EXT 20           // wave ext region 20x20
#define WSLICE 400       // EXT*EXT, also shh slice (20 rows x 16 cols, stride 20)
#define LROWS 32         // TH+16
#define LCOLS 80         // TW+16
#define NPIX (LROWS*LCOLS)

// Gaussian patch kernel, normalized separable taps gn = g/sum(g)
#define G0 0.05448868454910367f
#define G1 0.24420134203151178f
#define G2 0.40261994689466440f
// horizontal pass taps pre-multiplied by 1/3 (channel mean)
#define B0 0.01816289484970122f
#define B1 0.08140044734383726f
#define B2 0.13420664896488813f

#define MAD_INV 1.4826022185056018f   // 1/0.6744897501960817
#define LOG2E   1.4426950408889634f

typedef _Float16 half2v __attribute__((ext_vector_type(2)));
union PxU { uint2 u; half2v h[2]; };
union Q4  { uint4 u; half2v h[4]; };
#define H2(x) half2v{(_Float16)(x), (_Float16)(x)}

// ---------------------------------------------------------------- stage 1
__global__ void wavelet_hist(const float* __restrict__ x, int* __restrict__ hist) {
    int idx = blockIdx.x * 256 + threadIdx.x;
    if (idx >= HH_S * HH_S) return;
    int* hrep = hist + (blockIdx.x & (NREP - 1)) * 3 * NBINS;
    int i = (idx / HH_S) * 2;        // sampled: every other HH row/col
    int j = (idx - (idx / HH_S) * HH_S) * 2;
    const float k4[4] = {-0.48296291314469025f, 0.8365163037378079f,
                         -0.2241438680420134f, -0.12940952255126037f};
    float acc0 = 0.f, acc1 = 0.f, acc2 = 0.f;
    const bool fast = (j >= 2 && j <= 511);
#pragma unroll
    for (int a = 0; a < 4; ++a) {
        int sy = 2 * i + a - 3;                       // 'symmetric' pad
        sy = sy < 0 ? -sy - 1 : (sy >= IMG ? 2 * IMG - 1 - sy : sy);
        const float* row = x + (size_t)sy * IMG * 3;
        float r0, r1, r2;
        if (fast) {
            const float* p = row + (2 * j - 3) * 3;   // 12 consecutive floats
            float f0 = p[0], f1 = p[1], f2 = p[2], f3 = p[3];
            float f4 = p[4], f5 = p[5], f6 = p[6], f7 = p[7];
            float f8 = p[8], f9 = p[9], f10 = p[10], f11 = p[11];
            r0 = k4[0] * f0 + k4[1] * f3 + k4[2] * f6 + k4[3] * f9;
            r1 = k4[0] * f1 + k4[1] * f4 + k4[2] * f7 + k4[3] * f10;
            r2 = k4[0] * f2 + k4[1] * f5 + k4[2] * f8 + k4[3] * f11;
        } else {
            r0 = r1 = r2 = 0.f;
#pragma unroll
            for (int b = 0; b < 4; ++b) {
                int sx = 2 * j + b - 3;
                sx = sx < 0 ? -sx - 1 : (sx >= IMG ? 2 * IMG - 1 - sx : sx);
                const float* p = row + sx * 3;
                r0 += k4[b] * p[0]; r1 += k4[b] * p[1]; r2 += k4[b] * p[2];
            }
        }
        acc0 += k4[a] * r0; acc1 += k4[a] * r1; acc2 += k4[a] * r2;
    }
    int b0 = (int)(fabsf(acc0) * BIN_SCALE); b0 = b0 > NBINS - 1 ? NBINS - 1 : b0;
    int b1 = (int)(fabsf(acc1) * BIN_SCALE); b1 = b1 > NBINS - 1 ? NBINS - 1 : b1;
    int b2 = (int)(fabsf(acc2) * BIN_SCALE); b2 = b2 > NBINS - 1 ? NBINS - 1 : b2;
    atomicAdd(&hrep[b0], 1);
    atomicAdd(&hrep[NBINS + b1], 1);
    atomicAdd(&hrep[2 * NBINS + b2], 1);
}

// ---------------------------------------------------------------- stage 2
__global__ void sigma_scan(const int* __restrict__ hist, float* __restrict__ scal) {
    __shared__ int   wsum[16];
    __shared__ float sres[4];   // [0]=median val, [2]=sigma accum
    const int t = threadIdx.x;          // 1024 threads, 4 bins each
    const int lane = t & 63, wid = t >> 6;
    for (int c = 0; c < 3; ++c) {
        const int* h = hist + c * NBINS;
        int cnt[4]; int tsum = 0;
#pragma unroll
        for (int b = 0; b < 4; ++b) {
            int bin = t * 4 + b, s = 0;
#pragma unroll
            for (int r = 0; r < NREP; ++r) s += h[r * 3 * NBINS + bin];
            cnt[b] = s; tsum += s;
        }
        // wave-inclusive scan of tsum
        int incl = tsum;
#pragma unroll
        for (int o = 1; o < 64; o <<= 1) {
            int v = __shfl_up(incl, o);
            if (lane >= o) incl += v;
        }
        if (lane == 63) wsum[wid] = incl;
        __syncthreads();
        if (wid == 0) {
            int v = (lane < 16) ? wsum[lane] : 0;
            int inc = v;
#pragma unroll
            for (int o = 1; o < 16; o <<= 1) {
                int u = __shfl_up(inc, o);
                if (lane >= o) inc += u;
            }
            if (lane < 16) wsum[lane] = inc - v;     // exclusive wave base
        }
        __syncthreads();
        int cum = wsum[wid] + incl - tsum;           // exclusive prefix
#pragma unroll
        for (int b = 0; b < 4; ++b) {
            int nc = cum + cnt[b];
            float v = (t * 4 + b + 0.5f) * (1.0f / BIN_SCALE);
            if (cum < MED_K && nc >= MED_K) sres[0] = v;
            cum = nc;
        }
        __syncthreads();
        if (t == 0) {
            float prev = (c == 0) ? 0.f : sres[2];
            sres[2] = prev + sres[0] * MAD_INV;
        }
        __syncthreads();
    }
    if (t == 0) {
        float sigma = sres[2] * (1.0f / 3.0f);
        float hw = 0.8f * sigma;
        scal[0] = 2.0f * sigma * sigma;      // var
        scal[1] = LOG2E / (hw * hw);         // log2(e)/h^2  (for exp2f)
    }
}

// ---------------------------------------------------------------- stage 3
__device__ __forceinline__ float diff2(half2v a01, half2v a2, half2v b01, half2v b2) {
#if __has_builtin(__builtin_amdgcn_fdot2)
    half2v e01 = a01 - b01;          // v_pk_add_f16 w/ neg
    half2v e2  = a2  - b2;           // high halves are 0 on both sides
    return __builtin_amdgcn_fdot2(e01, e01,
           __builtin_amdgcn_fdot2(e2, e2, 0.f, false), false);
#else
    float e0 = (float)a01[0] - (float)b01[0];
    float e1 = (float)a01[1] - (float)b01[1];
    float e2 = (float)a2[0]  - (float)b2[0];
    return e0 * e0 + e1 * e1 + e2 * e2;
#endif
}

__device__ __forceinline__ half2v pack2(float a, float b) {
#if __has_builtin(__builtin_amdgcn_cvt_pkrtz)
    return __builtin_bit_cast(half2v, __builtin_amdgcn_cvt_pkrtz(a, b));
#else
    return half2v{(_Float16)a, (_Float16)b};
#endif
}

__launch_bounds__(256, 4)
__global__ void nlm_main(const float* __restrict__ x,
                         const float* __restrict__ scal,
                         float* __restrict__ out) {
    __shared__ __align__(16) uint2  spx[NPIX];          // packed half RGB (RO)
    __shared__ __align__(16) half2v sdh[4 * WSLICE];    // wave-private diff^2
    __shared__ __align__(16) half2v shh[4 * WSLICE];    // wave-private h-conv

    const int tid = threadIdx.x;
    const int X0 = blockIdx.x * TW;
    const int Y0 = blockIdx.y * TH;
    const int wv   = tid >> 6;        // wave id 0..3
    const int lane = tid & 63;
    const int wx   = wv * WTS;        // wave tile x base within block tile

    // --- load reflect-padded pixel tile, pack RGB -> 3xfp16 in uint2
    for (int l = tid; l < NPIX; l += 256) {
        int rr = l / LCOLS;
        int cc = l - rr * LCOLS;
        int sy = Y0 + rr - 8;                           // 'reflect' pad
        sy = sy < 0 ? -sy : (sy >= IMG ? 2 * IMG - 2 - sy : sy);
        int sc = X0 + cc - 8;
        sc = sc < 0 ? -sc : (sc >= IMG ? 2 * IMG - 2 - sc : sc);
        const float* p = x + ((size_t)sy * IMG + sc) * 3;
        uint2 u;
        u.x = (unsigned)__half_as_ushort(__float2half_rn(p[0])) |
              ((unsigned)__half_as_ushort(__float2half_rn(p[1])) << 16);
        u.y = (unsigned)__half_as_ushort(__float2half_rn(p[2]));  // hi 16 = 0
        spx[l] = u;
    }

    const float var  = scal[0];
    const float ih2l = scal[1];

    const int c  = lane & 15;         // output col within wave tile
    const int q  = lane >> 4;         // row-group: output rows 4q..4q+3
    float a0x = 0, a0y = 0, a0z = 0, w0s = 0;
    float a1x = 0, a1y = 0, a1z = 0, w1s = 0;
    float a2x = 0, a2y = 0, a2z = 0, w2s = 0;
    float a3x = 0, a3y = 0, a3z = 0, w3s = 0;

    __syncthreads();   // the ONLY block barrier: spx is read-only from here

    // --- register-cache ext-region center values for phase A
    // wave ext: rows/cols -2..17 rel to wave tile; lane owns idx, idx+64, ...
    half2v c01[7], c2[7];
    int    rb[7];
#pragma unroll
    for (int k = 0; k < 7; ++k) {
        int idx = lane + k * 64;
        int v = idx < WSLICE ? idx : 0;
        int ri = v / EXT;
        int ci = v - ri * EXT;
        rb[k] = (ri + 6) * LCOLS + (wx + ci + 6);
        PxU p; p.u = spx[rb[k]];
        c01[k] = p.h[0]; c2[k] = p.h[1];
    }

    const half2v B0h = H2(B0), B1h = H2(B1), B2h = H2(B2);
    const half2v G0h = H2(G0), G1h = H2(G1), G2h = H2(G2);

    const int sb = wv * WSLICE;       // this wave's sdh/shh slice base

    // ---- pair body: offsets (oy1,ox1) and (oy2,ox2) packed as half2.
    // MERGED: (oy2,ox2) == (oy1,ox1+1) -> adjacent spx reads.
    // NO BARRIERS: all sdh/shh deps are same-wave (in-order LDS).
    auto pair_body = [&](auto mtag, int oy1, int ox1, int oy2, int ox2) {
        constexpr bool MERGED = decltype(mtag)::value;
        const int doff1 = oy1 * LCOLS + ox1;
        const int doff2 = oy2 * LCOLS + ox2;

        // -------- phase A: diff^2 on 20x20 ext, one packed b32 write
#pragma unroll
        for (int k = 0; k < 7; ++k) {
            if (k < 6 || lane < WSLICE - 6 * 64) {
                int a1 = rb[k] + doff1;
                PxU p1, p2;
                p1.u = spx[a1];
                if constexpr (MERGED) p2.u = spx[a1 + 1];
                else                  p2.u = spx[rb[k] + doff2];
                float d1 = diff2(c01[k], c2[k], p1.h[0], p1.h[1]);
                float d2 = diff2(c01[k], c2[k], p2.h[0], p2.h[1]);
                sdh[sb + lane + k * 64] = pack2(d1, d2);
            }
        }

        // -------- phase B: packed horizontal conv, 80 tasks (20 rows x 4)
#pragma unroll
        for (int it = 0; it < 2; ++it) {
            int t = lane + it * 64;
            if (it == 0 || lane < 16) {
                int row = t >> 2, g = t & 3;
                const Q4* pa = (const Q4*)&sdh[sb + row * EXT + g * 4];
                Q4 a = pa[0], b = pa[1], o;
                o.h[0] = B0h * a.h[0] + B1h * a.h[1] + B2h * a.h[2] + B1h * a.h[3] + B0h * b.h[0];
                o.h[1] = B0h * a.h[1] + B1h * a.h[2] + B2h * a.h[3] + B1h * b.h[0] + B0h * b.h[1];
                o.h[2] = B0h * a.h[2] + B1h * a.h[3] + B2h * b.h[0] + B1h * b.h[1] + B0h * b.h[2];
                o.h[3] = B0h * a.h[3] + B1h * b.h[0] + B2h * b.h[1] + B1h * b.h[2] + B0h * b.h[3];
                *(uint4*)&shh[sb + row * EXT + g * 4] = o.u;
            }
        }

        // -------- phase C: packed vertical conv + 8 weights + accumulate
        {
            const int hb = sb + c;
            half2v s0 = shh[hb + (4 * q + 0) * EXT];
            half2v s1 = shh[hb + (4 * q + 1) * EXT];
            half2v s2 = shh[hb + (4 * q + 2) * EXT];
            half2v s3 = shh[hb + (4 * q + 3) * EXT];
            half2v s4 = shh[hb + (4 * q + 4) * EXT];
            half2v s5 = shh[hb + (4 * q + 5) * EXT];
            half2v s6 = shh[hb + (4 * q + 6) * EXT];
            half2v s7 = shh[hb + (4 * q + 7) * EXT];
            half2v d0 = G0h * s0 + G1h * s1 + G2h * s2 + G1h * s3 + G0h * s4;
            half2v d1 = G0h * s1 + G1h * s2 + G2h * s3 + G1h * s4 + G0h * s5;
            half2v d2 = G0h * s2 + G1h * s3 + G2h * s4 + G1h * s5 + G0h * s6;
            half2v d3 = G0h * s3 + G1h * s4 + G2h * s5 + G1h * s6 + G0h * s7;
            float w0a = exp2f(fminf(var - (float)d0[0], 0.f) * ih2l);
            float w0b = exp2f(fminf(var - (float)d0[1], 0.f) * ih2l);
            float w1a = exp2f(fminf(var - (float)d1[0], 0.f) * ih2l);
            float w1b = exp2f(fminf(var - (float)d1[1], 0.f) * ih2l);
            float w2a = exp2f(fminf(var - (float)d2[0], 0.f) * ih2l);
            float w2b = exp2f(fminf(var - (float)d2[1], 0.f) * ih2l);
            float w3a = exp2f(fminf(var - (float)d3[0], 0.f) * ih2l);
            float w3b = exp2f(fminf(var - (float)d3[1], 0.f) * ih2l);
            int cb1 = (4 * q + 8 + oy1) * LCOLS + (wx + c + 8 + ox1);
            PxU qa0, qa1, qa2, qa3, qb0, qb1, qb2, qb3;
            if constexpr (MERGED) {
                qa0.u = spx[cb1];             qb0.u = spx[cb1 + 1];
                qa1.u = spx[cb1 + LCOLS];     qb1.u = spx[cb1 + LCOLS + 1];
                qa2.u = spx[cb1 + 2 * LCOLS]; qb2.u = spx[cb1 + 2 * LCOLS + 1];
                qa3.u = spx[cb1 + 3 * LCOLS]; qb3.u = spx[cb1 + 3 * LCOLS + 1];
            } else {
                int cb2 = (4 * q + 8 + oy2) * LCOLS + (wx + c + 8 + ox2);
                qa0.u = spx[cb1];             qb0.u = spx[cb2];
                qa1.u = spx[cb1 + LCOLS];     qb1.u = spx[cb2 + LCOLS];
                qa2.u = spx[cb1 + 2 * LCOLS]; qb2.u = spx[cb2 + 2 * LCOLS];
                qa3.u = spx[cb1 + 3 * LCOLS]; qb3.u = spx[cb2 + 3 * LCOLS];
            }
            a0x += w0a * (float)qa0.h[0][0] + w0b * (float)qb0.h[0][0];
            a0y += w0a * (float)qa0.h[0][1] + w0b * (float)qb0.h[0][1];
            a0z += w0a * (float)qa0.h[1][0] + w0b * (float)qb0.h[1][0];
            a1x += w1a * (float)qa1.h[0][0] + w1b * (float)qb1.h[0][0];
            a1y += w1a * (float)qa1.h[0][1] + w1b * (float)qb1.h[0][1];
            a1z += w1a * (float)qa1.h[1][0] + w1b * (float)qb1.h[1][0];
            a2x += w2a * (float)qa2.h[0][0] + w2b * (float)qb2.h[0][0];
            a2y += w2a * (float)qa2.h[0][1] + w2b * (float)qb2.h[0][1];
            a2z += w2a * (float)qa2.h[1][0] + w2b * (float)qb2.h[1][0];
            a3x += w3a * (float)qa3.h[0][0] + w3b * (float)qb3.h[0][0];
            a3y += w3a * (float)qa3.h[0][1] + w3b * (float)qb3.h[0][1];
            a3z += w3a * (float)qa3.h[1][0] + w3b * (float)qb3.h[1][0];
            w0s += w0a + w0b; w1s += w1a + w1b;
            w2s += w2a + w2b; w3s += w3a + w3b;
        }
    };

    // ---- part 1: 78 same-row adjacent pairs (merged spx reads)
#pragma unroll 1
    for (int r = 0; r < 13; ++r) {
        const int oy = r - 6;
#pragma unroll 1
        for (int p = 0; p < 6; ++p) {
            int ox1 = (r == 6) ? ((p < 3) ? (-6 + 2 * p) : (2 * p - 5))
                               : (-6 + 2 * p);
            pair_body(std::integral_constant<bool, true>{}, oy, ox1, oy, ox1 + 1);
        }
    }
    // ---- part 2: 12 row-end singles (oy,6), oy != 0, as 6 generic pairs
#pragma unroll 1
    for (int p = 0; p < 6; ++p) {
        int l0 = 2 * p, l1 = 2 * p + 1;
        int oyA = (l0 < 6) ? l0 - 6 : l0 - 5;
        int oyB = (l1 < 6) ? l1 - 6 : l1 - 5;
        pair_body(std::integral_constant<bool, false>{}, oyA, 6, oyB, 6);
    }

    // -------- offset (0,0): d=0 -> w=1, value = center pixel
    {
        int cb = (4 * q + 8) * LCOLS + (wx + c + 8);
        PxU p0, p1, p2, p3;
        p0.u = spx[cb];             p1.u = spx[cb + LCOLS];
        p2.u = spx[cb + 2 * LCOLS]; p3.u = spx[cb + 3 * LCOLS];
        a0x += (float)p0.h[0][0]; a0y += (float)p0.h[0][1]; a0z += (float)p0.h[1][0];
        a1x += (float)p1.h[0][0]; a1y += (float)p1.h[0][1]; a1z += (float)p1.h[1][0];
        a2x += (float)p2.h[0][0]; a2y += (float)p2.h[0][1]; a2z += (float)p2.h[1][0];
        a3x += (float)p3.h[0][0]; a3y += (float)p3.h[0][1]; a3z += (float)p3.h[1][0];
        w0s += 1.f; w1s += 1.f; w2s += 1.f; w3s += 1.f;
    }

    // -------- epilogue: wave writes its 16x16 tile
    {
        int col = X0 + wx + c;
        int p0 = ((Y0 + 4 * q + 0) * IMG + col) * 3;
        int p1 = ((Y0 + 4 * q + 1) * IMG + col) * 3;
        int p2 = ((Y0 + 4 * q + 2) * IMG + col) * 3;
        int p3 = ((Y0 + 4 * q + 3) * IMG + col) * 3;
        float r0 = 1.f / w0s, r1 = 1.f / w1s, r2 = 1.f / w2s, r3 = 1.f / w3s;
        out[p0 + 0] = a0x * r0; out[p0 + 1] = a0y * r0; out[p0 + 2] = a0z * r0;
        out[p1 + 0] = a1x * r1; out[p1 + 1] = a1y * r1; out[p1 + 2] = a1z * r1;
        out[p2 + 0] = a2x * r2; out[p2 + 1] = a2y * r2; out[p2 + 2] = a2z * r2;
        out[p3 + 0] = a3x * r3; out[p3 + 1] = a3y * r3; out[p3 + 2] = a3z * r3;
    }
}

// ---------------------------------------------------------------- launch
extern "C" void kernel_launch(void* const* d_in, const int* in_sizes, int n_in,
                              void* d_out, int out_size, void* d_ws, size_t ws_size,
                              hipStream_t stream) {
    const float* x = (const float*)d_in[0];
    float* out = (float*)d_out;
    float* scal = (float*)d_ws;                       // [0]=var, [1]=log2e/h^2
    int* hist = (int*)((char*)d_ws + 64);             // NREP x 3 x 4096 ints

    (void)hipMemsetAsync(hist, 0, NREP * 3 * NBINS * sizeof(int), stream);
    wavelet_hist<<<(HH_S * HH_S + 255) / 256, 256, 0, stream>>>(x, hist);
    sigma_scan<<<1, 1024, 0, stream>>>(hist, scal);
    dim3 grid(IMG / TW, IMG / TH);
    nlm_main<<<grid, 256, 0, stream>>>(x, scal, out);
}

// Round 10
// 235.995 us; speedup vs baseline: 1.2259x; 1.2259x over previous
//
#include <hip/hip_runtime.h>
#include <hip/hip_fp16.h>
#include <math.h>
#include <type_traits>

// ----------------------------------------------------------------------------
// NL-means denoise (skimage slow-mode math) + db2-wavelet sigma estimate.
// Stage 1: wavelet HH conv (stride-2 SAMPLED grid) -> hist (2 replicas)
// Stage 2: single-block shfl-scan -> per-channel median -> sigma
// Stage 3: tiled NLM with +/- OFFSET SYMMETRY (R10):
//   dist_{-o}(p) = dist_o(p-o)  =>  weight field computed ONCE per |o| on an
//   extended region serves both directions. 42 packed-half2 iterations cover
//   all 168 non-center offsets (4 directions each):
//     A: diff^2 (packed 2 offsets) on 42x80 ext  -> sds
//     B: horiz 5-tap (packed, /3 folded)         -> shh
//     W: vert 5-tap + exp2 weights on 38x76 ext  -> sw (aliases sds)
//     C: gather sw[p], sw[p-o1], sw[p-o2] + 4 px reads, accumulate 4 dirs
//   64x32 tile, 512 thr, 2 blocks/CU, LDS 61.5KB. 4 barriers/iter but each
//   phase ~2x fatter than R8 -> stall amortized. R9 post-mortem: barrier-free
//   waves regressed (3x conflicts + 17% extra A work); reverted to block
//   phases, attacked fundamental work instead.
// ----------------------------------------------------------------------------

#define IMG   1024
#define HH_S  257
#define NBINS 4096
#define NREP  2
#define BIN_SCALE 4096.0f
#define MED_K 33025      // n=257*257=66049 odd: median = a[33024] (0-based)

#define TW 64
#define TH 32
// spx: rows -8..39 (48) x cols -14..77 (92)
#define PROWS 48
#define PCOLS 92
#define NPIX (PROWS*PCOLS)           // 4416
#define PXB(r,c) (((r)+8)*PCOLS + ((c)+14))
// sd: rows -8..33 (42) x cols -8..71 (80)
#define DCOLS 80
#define ND 3360                      // 42*80
// sh: rows -8..33 (42) x cols -6..69 (76)
#define HCOLS 76
#define NH 3192                      // 42*76
// sw: rows -6..31 (38) x cols -6..69 (76), aliases sds
#define NW 2888                      // 38*76
#define SWB(r,c) (((r)+6)*HCOLS + ((c)+6))

// Gaussian patch kernel, normalized separable taps
#define G0 0.05448868454910367f
#define G1 0.24420134203151178f
#define G2 0.40261994689466440f
// horizontal pass taps pre-multiplied by 1/3 (channel mean)
#define B0 0.01816289484970122f
#define B1 0.08140044734383726f
#define B2 0.13420664896488813f

#define MAD_INV 1.4826022185056018f
#define LOG2E   1.4426950408889634f

typedef _Float16 half2v __attribute__((ext_vector_type(2)));
union PxU { uint2 u; half2v h[2]; };
union Q4  { uint4 u; half2v h[4]; };
#define H2(x) half2v{(_Float16)(x), (_Float16)(x)}

// ---------------------------------------------------------------- stage 1
__global__ void wavelet_hist(const float* __restrict__ x, int* __restrict__ hist) {
    int idx = blockIdx.x * 256 + threadIdx.x;
    if (idx >= HH_S * HH_S) return;
    int* hrep = hist + (blockIdx.x & (NREP - 1)) * 3 * NBINS;
    int i = (idx / HH_S) * 2;
    int j = (idx - (idx / HH_S) * HH_S) * 2;
    const float k4[4] = {-0.48296291314469025f, 0.8365163037378079f,
                         -0.2241438680420134f, -0.12940952255126037f};
    float acc0 = 0.f, acc1 = 0.f, acc2 = 0.f;
    const bool fast = (j >= 2 && j <= 511);
#pragma unroll
    for (int a = 0; a < 4; ++a) {
        int sy = 2 * i + a - 3;                       // 'symmetric' pad
        sy = sy < 0 ? -sy - 1 : (sy >= IMG ? 2 * IMG - 1 - sy : sy);
        const float* row = x + (size_t)sy * IMG * 3;
        float r0, r1, r2;
        if (fast) {
            const float* p = row + (2 * j - 3) * 3;
            float f0 = p[0], f1 = p[1], f2 = p[2], f3 = p[3];
            float f4 = p[4], f5 = p[5], f6 = p[6], f7 = p[7];
            float f8 = p[8], f9 = p[9], f10 = p[10], f11 = p[11];
            r0 = k4[0] * f0 + k4[1] * f3 + k4[2] * f6 + k4[3] * f9;
            r1 = k4[0] * f1 + k4[1] * f4 + k4[2] * f7 + k4[3] * f10;
            r2 = k4[0] * f2 + k4[1] * f5 + k4[2] * f8 + k4[3] * f11;
        } else {
            r0 = r1 = r2 = 0.f;
#pragma unroll
            for (int b = 0; b < 4; ++b) {
                int sx = 2 * j + b - 3;
                sx = sx < 0 ? -sx - 1 : (sx >= IMG ? 2 * IMG - 1 - sx : sx);
                const float* p = row + sx * 3;
                r0 += k4[b] * p[0]; r1 += k4[b] * p[1]; r2 += k4[b] * p[2];
            }
        }
        acc0 += k4[a] * r0; acc1 += k4[a] * r1; acc2 += k4[a] * r2;
    }
    int b0 = (int)(fabsf(acc0) * BIN_SCALE); b0 = b0 > NBINS - 1 ? NBINS - 1 : b0;
    int b1 = (int)(fabsf(acc1) * BIN_SCALE); b1 = b1 > NBINS - 1 ? NBINS - 1 : b1;
    int b2 = (int)(fabsf(acc2) * BIN_SCALE); b2 = b2 > NBINS - 1 ? NBINS - 1 : b2;
    atomicAdd(&hrep[b0], 1);
    atomicAdd(&hrep[NBINS + b1], 1);
    atomicAdd(&hrep[2 * NBINS + b2], 1);
}

// ---------------------------------------------------------------- stage 2
__global__ void sigma_scan(const int* __restrict__ hist, float* __restrict__ scal) {
    __shared__ int   wsum[16];
    __shared__ float sres[4];
    const int t = threadIdx.x;
    const int lane = t & 63, wid = t >> 6;
    for (int c = 0; c < 3; ++c) {
        const int* h = hist + c * NBINS;
        int cnt[4]; int tsum = 0;
#pragma unroll
        for (int b = 0; b < 4; ++b) {
            int bin = t * 4 + b, s = 0;
#pragma unroll
            for (int r = 0; r < NREP; ++r) s += h[r * 3 * NBINS + bin];
            cnt[b] = s; tsum += s;
        }
        int incl = tsum;
#pragma unroll
        for (int o = 1; o < 64; o <<= 1) {
            int v = __shfl_up(incl, o);
            if (lane >= o) incl += v;
        }
        if (lane == 63) wsum[wid] = incl;
        __syncthreads();
        if (wid == 0) {
            int v = (lane < 16) ? wsum[lane] : 0;
            int inc = v;
#pragma unroll
            for (int o = 1; o < 16; o <<= 1) {
                int u = __shfl_up(inc, o);
                if (lane >= o) inc += u;
            }
            if (lane < 16) wsum[lane] = inc - v;
        }
        __syncthreads();
        int cum = wsum[wid] + incl - tsum;
#pragma unroll
        for (int b = 0; b < 4; ++b) {
            int nc = cum + cnt[b];
            float v = (t * 4 + b + 0.5f) * (1.0f / BIN_SCALE);
            if (cum < MED_K && nc >= MED_K) sres[0] = v;
            cum = nc;
        }
        __syncthreads();
        if (t == 0) {
            float prev = (c == 0) ? 0.f : sres[2];
            sres[2] = prev + sres[0] * MAD_INV;
        }
        __syncthreads();
    }
    if (t == 0) {
        float sigma = sres[2] * (1.0f / 3.0f);
        float hw = 0.8f * sigma;
        scal[0] = 2.0f * sigma * sigma;      // var
        scal[1] = LOG2E / (hw * hw);         // log2(e)/h^2
    }
}

// ---------------------------------------------------------------- stage 3
__device__ __forceinline__ float diff2(half2v a01, half2v a2, half2v b01, half2v b2) {
#if __has_builtin(__builtin_amdgcn_fdot2)
    half2v e01 = a01 - b01;
    half2v e2  = a2  - b2;
    return __builtin_amdgcn_fdot2(e01, e01,
           __builtin_amdgcn_fdot2(e2, e2, 0.f, false), false);
#else
    float e0 = (float)a01[0] - (float)b01[0];
    float e1 = (float)a01[1] - (float)b01[1];
    float e2 = (float)a2[0]  - (float)b2[0];
    return e0 * e0 + e1 * e1 + e2 * e2;
#endif
}

__device__ __forceinline__ half2v pack2(float a, float b) {
#if __has_builtin(__builtin_amdgcn_cvt_pkrtz)
    return __builtin_bit_cast(half2v, __builtin_amdgcn_cvt_pkrtz(a, b));
#else
    return half2v{(_Float16)a, (_Float16)b};
#endif
}

__launch_bounds__(512, 4)
__global__ void nlm_main(const float* __restrict__ x,
                         const float* __restrict__ scal,
                         float* __restrict__ out) {
    __shared__ __align__(16) uint2  spx[NPIX];   // packed half RGB (RO in loop)
    __shared__ __align__(16) half2v sds[ND];     // diff^2 pairs; aliased as sw
    __shared__ __align__(16) half2v shh[NH];     // horiz-conv pairs

    const int tid = threadIdx.x;
    const int X0 = blockIdx.x * TW;
    const int Y0 = blockIdx.y * TH;

    // --- load reflect-padded pixel tile, pack RGB -> 3xfp16 in uint2
    for (int l = tid; l < NPIX; l += 512) {
        int rr = l / PCOLS;
        int cc = l - rr * PCOLS;
        int sy = Y0 + rr - 8;
        sy = sy < 0 ? -sy : (sy >= IMG ? 2 * IMG - 2 - sy : sy);
        int sc = X0 + cc - 14;
        sc = sc < 0 ? -sc : (sc >= IMG ? 2 * IMG - 2 - sc : sc);
        const float* p = x + ((size_t)sy * IMG + sc) * 3;
        uint2 u;
        u.x = (unsigned)__half_as_ushort(__float2half_rn(p[0])) |
              ((unsigned)__half_as_ushort(__float2half_rn(p[1])) << 16);
        u.y = (unsigned)__half_as_ushort(__float2half_rn(p[2]));  // hi 16 = 0
        spx[l] = u;
    }

    const float var  = scal[0];
    const float ih2l = scal[1];

    const int c  = tid & 63;          // output col within tile
    const int rg = (tid >> 6) * 4;    // first of 4 output rows (0..28)
    float accx[4] = {0, 0, 0, 0}, accy[4] = {0, 0, 0, 0};
    float accz[4] = {0, 0, 0, 0}, accw[4] = {0, 0, 0, 0};

    __syncthreads();

    // --- register-cache center values + spx base index for phase A tasks
    half2v ctr01[7], ctr2[7];
    int    pb[7];
#pragma unroll
    for (int k = 0; k < 7; ++k) {
        int i = (k < 6 || tid < ND - 6 * 512) ? tid + k * 512 : 0;
        int dr = i / DCOLS;
        int dc = i - dr * DCOLS;
        pb[k] = dr * PCOLS + dc + 6;   // PXB(dr-8, dc-8)
        PxU p; p.u = spx[pb[k]];
        ctr01[k] = p.h[0]; ctr2[k] = p.h[1];
    }

    const half2v B0h = H2(B0), B1h = H2(B1), B2h = H2(B2);
    const half2v G0h = H2(G0), G1h = H2(G1), G2h = H2(G2);

    // ---- pair body: offsets o1=(oy1,ox1), o2=(oy2,ox2) packed as half2;
    // each serves BOTH +o and -o directions via the symmetry
    // dist_{-o}(p) = dist_o(p-o). MERGED: o2 == o1 + (0,1).
    auto pair_body = [&](auto mtag, int oy1, int ox1, int oy2, int ox2) {
        constexpr bool MERGED = decltype(mtag)::value;
        const int d1off = oy1 * PCOLS + ox1;
        const int d2off = oy2 * PCOLS + ox2;

        // -------- phase A: packed diff^2 on 42x80 ext region -> sds
#pragma unroll
        for (int k = 0; k < 7; ++k) {
            if (k < 6 || tid < ND - 6 * 512) {
                PxU p1, p2;
                p1.u = spx[pb[k] + d1off];
                if constexpr (MERGED) p2.u = spx[pb[k] + d1off + 1];
                else                  p2.u = spx[pb[k] + d2off];
                float da = diff2(ctr01[k], ctr2[k], p1.h[0], p1.h[1]);
                float db = diff2(ctr01[k], ctr2[k], p2.h[0], p2.h[1]);
                sds[tid + k * 512] = pack2(da, db);
            }
        }
        __syncthreads();

        // -------- phase B: packed horizontal conv -> shh (798 b128 tasks)
        {
            int row = tid / 19, g = tid - row * 19;
            int b = row * DCOLS + 4 * g;
            Q4 a, q, o;
            a.u = *(const uint4*)&sds[b];
            q.u = *(const uint4*)&sds[b + 4];
            o.h[0] = B0h * a.h[0] + B1h * a.h[1] + B2h * a.h[2] + B1h * a.h[3] + B0h * q.h[0];
            o.h[1] = B0h * a.h[1] + B1h * a.h[2] + B2h * a.h[3] + B1h * q.h[0] + B0h * q.h[1];
            o.h[2] = B0h * a.h[2] + B1h * a.h[3] + B2h * q.h[0] + B1h * q.h[1] + B0h * q.h[2];
            o.h[3] = B0h * a.h[3] + B1h * q.h[0] + B2h * q.h[1] + B1h * q.h[2] + B0h * q.h[3];
            *(uint4*)&shh[row * HCOLS + 4 * g] = o.u;
            if (tid < 798 - 512) {
                int j2 = tid + 512;
                int row2 = j2 / 19, g2 = j2 - row2 * 19;
                int b2 = row2 * DCOLS + 4 * g2;
                a.u = *(const uint4*)&sds[b2];
                q.u = *(const uint4*)&sds[b2 + 4];
                o.h[0] = B0h * a.h[0] + B1h * a.h[1] + B2h * a.h[2] + B1h * a.h[3] + B0h * q.h[0];
                o.h[1] = B0h * a.h[1] + B1h * a.h[2] + B2h * a.h[3] + B1h * q.h[0] + B0h * q.h[1];
                o.h[2] = B0h * a.h[2] + B1h * a.h[3] + B2h * q.h[0] + B1h * q.h[1] + B0h * q.h[2];
                o.h[3] = B0h * a.h[3] + B1h * q.h[0] + B2h * q.h[1] + B1h * q.h[2] + B0h * q.h[3];
                *(uint4*)&shh[row2 * HCOLS + 4 * g2] = o.u;
            }
        }
        __syncthreads();

        // -------- phase W: vert conv + exp2 weights on 38x76 -> sw (=sds)
#pragma unroll
        for (int k = 0; k < 6; ++k) {
            if (k < 5 || tid < NW - 5 * 512) {
                int m = tid + k * 512;
                half2v s0 = shh[m];
                half2v s1 = shh[m + HCOLS];
                half2v s2 = shh[m + 2 * HCOLS];
                half2v s3 = shh[m + 3 * HCOLS];
                half2v s4 = shh[m + 4 * HCOLS];
                half2v d = G0h * s0 + G1h * s1 + G2h * s2 + G1h * s3 + G0h * s4;
                float wa = exp2f(fminf(var - (float)d[0], 0.f) * ih2l);
                float wb = exp2f(fminf(var - (float)d[1], 0.f) * ih2l);
                sds[m] = pack2(wa, wb);
            }
        }
        __syncthreads();

        // -------- phase C: accumulate 4 directions per packed pair
#pragma unroll
        for (int j = 0; j < 4; ++j) {
            int r = rg + j;
            half2v wp = sds[SWB(r, c)];
            _Float16 wm1h, wm2h;
            PxU pa, pbx, pm1, pm2;
            if constexpr (MERGED) {
                int wmb = SWB(r - oy1, c - ox1);
                wm1h = sds[wmb][0];
                wm2h = sds[wmb - 1][1];
                int ab = PXB(r + oy1, c + ox1);
                pa.u  = spx[ab]; pbx.u = spx[ab + 1];
                int mb = PXB(r - oy1, c - ox1);
                pm1.u = spx[mb]; pm2.u = spx[mb - 1];
            } else {
                wm1h  = sds[SWB(r - oy1, c - ox1)][0];
                wm2h  = sds[SWB(r - oy2, c - ox2)][1];
                pa.u  = spx[PXB(r + oy1, c + ox1)];
                pbx.u = spx[PXB(r + oy2, c + ox2)];
                pm1.u = spx[PXB(r - oy1, c - ox1)];
                pm2.u = spx[PXB(r - oy2, c - ox2)];
            }
            float w1 = (float)wp[0], w2 = (float)wp[1];
            float f1 = (float)wm1h, f2 = (float)wm2h;
            accx[j] += w1 * (float)pa.h[0][0] + w2 * (float)pbx.h[0][0]
                     + f1 * (float)pm1.h[0][0] + f2 * (float)pm2.h[0][0];
            accy[j] += w1 * (float)pa.h[0][1] + w2 * (float)pbx.h[0][1]
                     + f1 * (float)pm1.h[0][1] + f2 * (float)pm2.h[0][1];
            accz[j] += w1 * (float)pa.h[1][0] + w2 * (float)pbx.h[1][0]
                     + f1 * (float)pm1.h[1][0] + f2 * (float)pm2.h[1][0];
            accw[j] += (w1 + w2) + (f1 + f2);
        }
        __syncthreads();   // protect sw (=sds) from next iteration's A writes
    };

    // ---- 42 iterations cover 84 representative offsets x 2 directions:
    // oy=0: ox 1..6 as merged pairs (1,2),(3,4),(5,6)
#pragma unroll 1
    for (int pi = 0; pi < 3; ++pi)
        pair_body(std::integral_constant<bool, true>{}, 0, 1 + 2 * pi, 0, 2 + 2 * pi);
    // oy=1..6: ox -6..5 as 6 merged pairs per row
#pragma unroll 1
    for (int oy = 1; oy <= 6; ++oy)
#pragma unroll 1
        for (int pi = 0; pi < 6; ++pi)
            pair_body(std::integral_constant<bool, true>{}, oy, -6 + 2 * pi, oy, -5 + 2 * pi);
    // leftovers (oy,6) for oy=1..6 as 3 generic pairs
#pragma unroll 1
    for (int p = 0; p < 3; ++p)
        pair_body(std::integral_constant<bool, false>{}, 2 * p + 1, 6, 2 * p + 2, 6);

    // -------- offset (0,0): d=0 -> w=1
#pragma unroll
    for (int j = 0; j < 4; ++j) {
        PxU p; p.u = spx[PXB(rg + j, c)];
        accx[j] += (float)p.h[0][0];
        accy[j] += (float)p.h[0][1];
        accz[j] += (float)p.h[1][0];
        accw[j] += 1.f;
    }

    // -------- epilogue
#pragma unroll
    for (int j = 0; j < 4; ++j) {
        int po = ((Y0 + rg + j) * IMG + X0 + c) * 3;
        float rw = 1.f / accw[j];
        out[po + 0] = accx[j] * rw;
        out[po + 1] = accy[j] * rw;
        out[po + 2] = accz[j] * rw;
    }
}

// ---------------------------------------------------------------- launch
extern "C" void kernel_launch(void* const* d_in, const int* in_sizes, int n_in,
                              void* d_out, int out_size, void* d_ws, size_t ws_size,
                              hipStream_t stream) {
    const float* x = (const float*)d_in[0];
    float* out = (float*)d_out;
    float* scal = (float*)d_ws;                       // [0]=var, [1]=log2e/h^2
    int* hist = (int*)((char*)d_ws + 64);             // NREP x 3 x 4096 ints

    (void)hipMemsetAsync(hist, 0, NREP * 3 * NBINS * sizeof(int), stream);
    wavelet_hist<<<(HH_S * HH_S + 255) / 256, 256, 0, stream>>>(x, hist);
    sigma_scan<<<1, 1024, 0, stream>>>(hist, scal);
    dim3 grid(IMG / TW, IMG / TH);
    nlm_main<<<grid, 512, 0, stream>>>(x, scal, out);
}

// Round 12
// 232.548 us; speedup vs baseline: 1.2441x; 1.0148x over previous
//
#include <hip/hip_runtime.h>
#include <hip/hip_fp16.h>
#include <math.h>
#include <type_traits>

// ----------------------------------------------------------------------------
// NL-means denoise (skimage slow-mode math) + db2-wavelet sigma estimate.
// Stage 1: wavelet HH conv (stride-2 SAMPLED grid) -> hist (2 replicas)
// Stage 2: 3 blocks (one per channel) shfl-scan -> median -> atomicAdd sigsum
// Stage 3: tiled NLM with +/- offset symmetry (R10: 42 iters cover 168 offs):
//     A: diff^2 (packed 2 offsets) on 42x80 ext  -> sds
//     B: horiz 5-tap (packed, /3 folded)         -> shh
//     W: vert 5-tap + exp2 weights on 38x76 ext  -> sw (aliases sds)
//        [R11: column-PAIR b64 tasks; R12 FIX: k=2 guard used t<NWP-1024
//         (always false) -> last 420 tasks never ran -> stale weights,
//         absmax 0.117. Correct guard: t < NWP.]
//     C: gather sw[p], sw[p-o1], sw[p-o2] + 4 px reads, accumulate 4 dirs
// ----------------------------------------------------------------------------

#define IMG   1024
#define HH_S  257
#define NBINS 4096
#define NREP  2
#define BIN_SCALE 4096.0f
#define MED_K 33025      // n=257*257=66049 odd: median = a[33024] (0-based)

#define TW 64
#define TH 32
// spx: rows -8..39 (48) x cols -14..77 (92)
#define PROWS 48
#define PCOLS 92
#define NPIX (PROWS*PCOLS)           // 4416
#define PXB(r,c) (((r)+8)*PCOLS + ((c)+14))
// sd: rows -8..33 (42) x cols -8..71 (80)
#define DCOLS 80
#define ND 3360                      // 42*80
// sh: rows -8..33 (42) x cols -6..69 (76)
#define HCOLS 76
#define NH 3192                      // 42*76
// sw: rows -6..31 (38) x cols -6..69 (76), aliases sds
#define NW 2888                      // 38*76
#define NWP 1444                     // 38 rows x 38 col-pairs
#define SWB(r,c) (((r)+6)*HCOLS + ((c)+6))

// Gaussian patch kernel, normalized separable taps
#define G0 0.05448868454910367f
#define G1 0.24420134203151178f
#define G2 0.40261994689466440f
// horizontal pass taps pre-multiplied by 1/3 (channel mean)
#define B0 0.01816289484970122f
#define B1 0.08140044734383726f
#define B2 0.13420664896488813f

#define MAD_INV 1.4826022185056018f
#define LOG2E   1.4426950408889634f

typedef _Float16 half2v __attribute__((ext_vector_type(2)));
union PxU { uint2 u; half2v h[2]; };
union Q4  { uint4 u; half2v h[4]; };
union Q2  { uint2 u; half2v h[2]; };
#define H2(x) half2v{(_Float16)(x), (_Float16)(x)}

// ---------------------------------------------------------------- stage 1
__global__ void wavelet_hist(const float* __restrict__ x, int* __restrict__ hist) {
    int idx = blockIdx.x * 256 + threadIdx.x;
    if (idx >= HH_S * HH_S) return;
    int* hrep = hist + (blockIdx.x & (NREP - 1)) * 3 * NBINS;
    int i = (idx / HH_S) * 2;
    int j = (idx - (idx / HH_S) * HH_S) * 2;
    const float k4[4] = {-0.48296291314469025f, 0.8365163037378079f,
                         -0.2241438680420134f, -0.12940952255126037f};
    float acc0 = 0.f, acc1 = 0.f, acc2 = 0.f;
    const bool fast = (j >= 2 && j <= 511);
#pragma unroll
    for (int a = 0; a < 4; ++a) {
        int sy = 2 * i + a - 3;                       // 'symmetric' pad
        sy = sy < 0 ? -sy - 1 : (sy >= IMG ? 2 * IMG - 1 - sy : sy);
        const float* row = x + (size_t)sy * IMG * 3;
        float r0, r1, r2;
        if (fast) {
            const float* p = row + (2 * j - 3) * 3;
            float f0 = p[0], f1 = p[1], f2 = p[2], f3 = p[3];
            float f4 = p[4], f5 = p[5], f6 = p[6], f7 = p[7];
            float f8 = p[8], f9 = p[9], f10 = p[10], f11 = p[11];
            r0 = k4[0] * f0 + k4[1] * f3 + k4[2] * f6 + k4[3] * f9;
            r1 = k4[0] * f1 + k4[1] * f4 + k4[2] * f7 + k4[3] * f10;
            r2 = k4[0] * f2 + k4[1] * f5 + k4[2] * f8 + k4[3] * f11;
        } else {
            r0 = r1 = r2 = 0.f;
#pragma unroll
            for (int b = 0; b < 4; ++b) {
                int sx = 2 * j + b - 3;
                sx = sx < 0 ? -sx - 1 : (sx >= IMG ? 2 * IMG - 1 - sx : sx);
                const float* p = row + sx * 3;
                r0 += k4[b] * p[0]; r1 += k4[b] * p[1]; r2 += k4[b] * p[2];
            }
        }
        acc0 += k4[a] * r0; acc1 += k4[a] * r1; acc2 += k4[a] * r2;
    }
    int b0 = (int)(fabsf(acc0) * BIN_SCALE); b0 = b0 > NBINS - 1 ? NBINS - 1 : b0;
    int b1 = (int)(fabsf(acc1) * BIN_SCALE); b1 = b1 > NBINS - 1 ? NBINS - 1 : b1;
    int b2 = (int)(fabsf(acc2) * BIN_SCALE); b2 = b2 > NBINS - 1 ? NBINS - 1 : b2;
    atomicAdd(&hrep[b0], 1);
    atomicAdd(&hrep[NBINS + b1], 1);
    atomicAdd(&hrep[2 * NBINS + b2], 1);
}

// ---------------------------------------------------------------- stage 2
// one block per channel; accumulates med*MAD_INV/3 into scal[0] (pre-zeroed)
__global__ void sigma_scan(const int* __restrict__ hist, float* __restrict__ scal) {
    __shared__ int   wsum[16];
    __shared__ float sres[1];
    const int t = threadIdx.x;
    const int lane = t & 63, wid = t >> 6;
    const int c = blockIdx.x;
    const int* h = hist + c * NBINS;
    int cnt[4]; int tsum = 0;
#pragma unroll
    for (int b = 0; b < 4; ++b) {
        int bin = t * 4 + b, s = 0;
#pragma unroll
        for (int r = 0; r < NREP; ++r) s += h[r * 3 * NBINS + bin];
        cnt[b] = s; tsum += s;
    }
    int incl = tsum;
#pragma unroll
    for (int o = 1; o < 64; o <<= 1) {
        int v = __shfl_up(incl, o);
        if (lane >= o) incl += v;
    }
    if (lane == 63) wsum[wid] = incl;
    __syncthreads();
    if (wid == 0) {
        int v = (lane < 16) ? wsum[lane] : 0;
        int inc = v;
#pragma unroll
        for (int o = 1; o < 16; o <<= 1) {
            int u = __shfl_up(inc, o);
            if (lane >= o) inc += u;
        }
        if (lane < 16) wsum[lane] = inc - v;
    }
    __syncthreads();
    int cum = wsum[wid] + incl - tsum;
#pragma unroll
    for (int b = 0; b < 4; ++b) {
        int nc = cum + cnt[b];
        float v = (t * 4 + b + 0.5f) * (1.0f / BIN_SCALE);
        if (cum < MED_K && nc >= MED_K) sres[0] = v;
        cum = nc;
    }
    __syncthreads();
    if (t == 0) atomicAdd(&scal[0], sres[0] * (MAD_INV / 3.0f));
}

// ---------------------------------------------------------------- stage 3
__device__ __forceinline__ float diff2(half2v a01, half2v a2, half2v b01, half2v b2) {
#if __has_builtin(__builtin_amdgcn_fdot2)
    half2v e01 = a01 - b01;
    half2v e2  = a2  - b2;
    return __builtin_amdgcn_fdot2(e01, e01,
           __builtin_amdgcn_fdot2(e2, e2, 0.f, false), false);
#else
    float e0 = (float)a01[0] - (float)b01[0];
    float e1 = (float)a01[1] - (float)b01[1];
    float e2 = (float)a2[0]  - (float)b2[0];
    return e0 * e0 + e1 * e1 + e2 * e2;
#endif
}

__device__ __forceinline__ half2v pack2(float a, float b) {
#if __has_builtin(__builtin_amdgcn_cvt_pkrtz)
    return __builtin_bit_cast(half2v, __builtin_amdgcn_cvt_pkrtz(a, b));
#else
    return half2v{(_Float16)a, (_Float16)b};
#endif
}

__launch_bounds__(512, 4)
__global__ void nlm_main(const float* __restrict__ x,
                         const float* __restrict__ scal,
                         float* __restrict__ out) {
    __shared__ __align__(16) uint2  spx[NPIX];   // packed half RGB (RO in loop)
    __shared__ __align__(16) half2v sds[ND];     // diff^2 pairs; aliased as sw
    __shared__ __align__(16) half2v shh[NH];     // horiz-conv pairs

    const int tid = threadIdx.x;
    const int X0 = blockIdx.x * TW;
    const int Y0 = blockIdx.y * TH;

    // --- load reflect-padded pixel tile, pack RGB -> 3xfp16 in uint2
    for (int l = tid; l < NPIX; l += 512) {
        int rr = l / PCOLS;
        int cc = l - rr * PCOLS;
        int sy = Y0 + rr - 8;
        sy = sy < 0 ? -sy : (sy >= IMG ? 2 * IMG - 2 - sy : sy);
        int sc = X0 + cc - 14;
        sc = sc < 0 ? -sc : (sc >= IMG ? 2 * IMG - 2 - sc : sc);
        const float* p = x + ((size_t)sy * IMG + sc) * 3;
        uint2 u;
        u.x = (unsigned)__half_as_ushort(__float2half_rn(p[0])) |
              ((unsigned)__half_as_ushort(__float2half_rn(p[1])) << 16);
        u.y = (unsigned)__half_as_ushort(__float2half_rn(p[2]));  // hi 16 = 0
        spx[l] = u;
    }

    const float sigma = scal[0];
    const float var   = 2.0f * sigma * sigma;
    const float ih2l  = LOG2E / (0.64f * sigma * sigma);   // h = 0.8*sigma

    const int c  = tid & 63;          // output col within tile
    const int rg = (tid >> 6) * 4;    // first of 4 output rows (0..28)
    float accx[4] = {0, 0, 0, 0}, accy[4] = {0, 0, 0, 0};
    float accz[4] = {0, 0, 0, 0}, accw[4] = {0, 0, 0, 0};

    __syncthreads();

    // --- register-cache center values + spx base index for phase A tasks
    half2v ctr01[7], ctr2[7];
    int    pb[7];
#pragma unroll
    for (int k = 0; k < 7; ++k) {
        int i = (k < 6 || tid < ND - 6 * 512) ? tid + k * 512 : 0;
        int dr = i / DCOLS;
        int dc = i - dr * DCOLS;
        pb[k] = dr * PCOLS + dc + 6;   // PXB(dr-8, dc-8)
        PxU p; p.u = spx[pb[k]];
        ctr01[k] = p.h[0]; ctr2[k] = p.h[1];
    }

    const half2v B0h = H2(B0), B1h = H2(B1), B2h = H2(B2);
    const half2v G0h = H2(G0), G1h = H2(G1), G2h = H2(G2);

    // ---- pair body: offsets o1=(oy1,ox1), o2=(oy2,ox2) packed as half2;
    // each serves BOTH +o and -o directions (dist_{-o}(p) = dist_o(p-o)).
    auto pair_body = [&](auto mtag, int oy1, int ox1, int oy2, int ox2) {
        constexpr bool MERGED = decltype(mtag)::value;
        const int d1off = oy1 * PCOLS + ox1;
        const int d2off = oy2 * PCOLS + ox2;

        // -------- phase A: packed diff^2 on 42x80 ext region -> sds
#pragma unroll
        for (int k = 0; k < 7; ++k) {
            if (k < 6 || tid < ND - 6 * 512) {
                PxU p1, p2;
                p1.u = spx[pb[k] + d1off];
                if constexpr (MERGED) p2.u = spx[pb[k] + d1off + 1];
                else                  p2.u = spx[pb[k] + d2off];
                float da = diff2(ctr01[k], ctr2[k], p1.h[0], p1.h[1]);
                float db = diff2(ctr01[k], ctr2[k], p2.h[0], p2.h[1]);
                sds[tid + k * 512] = pack2(da, db);
            }
        }
        __syncthreads();

        // -------- phase B: packed horizontal conv -> shh (798 b128 tasks)
        {
            int row = tid / 19, g = tid - row * 19;
            int b = row * DCOLS + 4 * g;
            Q4 a, q, o;
            a.u = *(const uint4*)&sds[b];
            q.u = *(const uint4*)&sds[b + 4];
            o.h[0] = B0h * a.h[0] + B1h * a.h[1] + B2h * a.h[2] + B1h * a.h[3] + B0h * q.h[0];
            o.h[1] = B0h * a.h[1] + B1h * a.h[2] + B2h * a.h[3] + B1h * q.h[0] + B0h * q.h[1];
            o.h[2] = B0h * a.h[2] + B1h * a.h[3] + B2h * q.h[0] + B1h * q.h[1] + B0h * q.h[2];
            o.h[3] = B0h * a.h[3] + B1h * q.h[0] + B2h * q.h[1] + B1h * q.h[2] + B0h * q.h[3];
            *(uint4*)&shh[row * HCOLS + 4 * g] = o.u;
            if (tid < 798 - 512) {
                int j2 = tid + 512;
                int row2 = j2 / 19, g2 = j2 - row2 * 19;
                int b2 = row2 * DCOLS + 4 * g2;
                a.u = *(const uint4*)&sds[b2];
                q.u = *(const uint4*)&sds[b2 + 4];
                o.h[0] = B0h * a.h[0] + B1h * a.h[1] + B2h * a.h[2] + B1h * a.h[3] + B0h * q.h[0];
                o.h[1] = B0h * a.h[1] + B1h * a.h[2] + B2h * a.h[3] + B1h * q.h[0] + B0h * q.h[1];
                o.h[2] = B0h * a.h[2] + B1h * a.h[3] + B2h * q.h[0] + B1h * q.h[1] + B0h * q.h[2];
                o.h[3] = B0h * a.h[3] + B1h * q.h[0] + B2h * q.h[1] + B1h * q.h[2] + B0h * q.h[3];
                *(uint4*)&shh[row2 * HCOLS + 4 * g2] = o.u;
            }
        }
        __syncthreads();

        // -------- phase W: vert conv + exp2 weights, COLUMN-PAIR b64 tasks
        // 1444 tasks = 38 rows x 38 col-pairs; math per column identical to
        // the b32 version. R12: guard fixed (t < NWP, was t < NWP-1024).
#pragma unroll
        for (int k = 0; k < 3; ++k) {
            int t = tid + k * 512;
            if (k < 2 || t < NWP) {
                int row = t / 38, cp = t - row * 38;
                int m = row * HCOLS + 2 * cp;
                Q2 s0, s1, s2, s3, s4, o;
                s0.u = *(const uint2*)&shh[m];
                s1.u = *(const uint2*)&shh[m + HCOLS];
                s2.u = *(const uint2*)&shh[m + 2 * HCOLS];
                s3.u = *(const uint2*)&shh[m + 3 * HCOLS];
                s4.u = *(const uint2*)&shh[m + 4 * HCOLS];
                half2v d0 = G0h * s0.h[0] + G1h * s1.h[0] + G2h * s2.h[0] + G1h * s3.h[0] + G0h * s4.h[0];
                half2v d1 = G0h * s0.h[1] + G1h * s1.h[1] + G2h * s2.h[1] + G1h * s3.h[1] + G0h * s4.h[1];
                o.h[0] = pack2(exp2f(fminf(var - (float)d0[0], 0.f) * ih2l),
                               exp2f(fminf(var - (float)d0[1], 0.f) * ih2l));
                o.h[1] = pack2(exp2f(fminf(var - (float)d1[0], 0.f) * ih2l),
                               exp2f(fminf(var - (float)d1[1], 0.f) * ih2l));
                *(uint2*)&sds[m] = o.u;
            }
        }
        __syncthreads();

        // -------- phase C: accumulate 4 directions per packed pair
#pragma unroll
        for (int j = 0; j < 4; ++j) {
            int r = rg + j;
            half2v wp = sds[SWB(r, c)];
            _Float16 wm1h, wm2h;
            PxU pa, pbx, pm1, pm2;
            if constexpr (MERGED) {
                int wmb = SWB(r - oy1, c - ox1);
                wm1h = sds[wmb][0];
                wm2h = sds[wmb - 1][1];
                int ab = PXB(r + oy1, c + ox1);
                pa.u  = spx[ab]; pbx.u = spx[ab + 1];
                int mb = PXB(r - oy1, c - ox1);
                pm1.u = spx[mb]; pm2.u = spx[mb - 1];
            } else {
                wm1h  = sds[SWB(r - oy1, c - ox1)][0];
                wm2h  = sds[SWB(r - oy2, c - ox2)][1];
                pa.u  = spx[PXB(r + oy1, c + ox1)];
                pbx.u = spx[PXB(r + oy2, c + ox2)];
                pm1.u = spx[PXB(r - oy1, c - ox1)];
                pm2.u = spx[PXB(r - oy2, c - ox2)];
            }
            float w1 = (float)wp[0], w2 = (float)wp[1];
            float f1 = (float)wm1h, f2 = (float)wm2h;
            accx[j] += w1 * (float)pa.h[0][0] + w2 * (float)pbx.h[0][0]
                     + f1 * (float)pm1.h[0][0] + f2 * (float)pm2.h[0][0];
            accy[j] += w1 * (float)pa.h[0][1] + w2 * (float)pbx.h[0][1]
                     + f1 * (float)pm1.h[0][1] + f2 * (float)pm2.h[0][1];
            accz[j] += w1 * (float)pa.h[1][0] + w2 * (float)pbx.h[1][0]
                     + f1 * (float)pm1.h[1][0] + f2 * (float)pm2.h[1][0];
            accw[j] += (w1 + w2) + (f1 + f2);
        }
        __syncthreads();   // protect sw (=sds) from next iteration's A writes
    };

    // ---- 42 iterations cover 84 representative offsets x 2 directions:
    // oy=0: ox 1..6 as merged pairs (1,2),(3,4),(5,6)
#pragma unroll 1
    for (int pi = 0; pi < 3; ++pi)
        pair_body(std::integral_constant<bool, true>{}, 0, 1 + 2 * pi, 0, 2 + 2 * pi);
    // oy=1..6: ox -6..5 as 6 merged pairs per row
#pragma unroll 1
    for (int oy = 1; oy <= 6; ++oy)
#pragma unroll 1
        for (int pi = 0; pi < 6; ++pi)
            pair_body(std::integral_constant<bool, true>{}, oy, -6 + 2 * pi, oy, -5 + 2 * pi);
    // leftovers (oy,6) for oy=1..6 as 3 generic pairs
#pragma unroll 1
    for (int p = 0; p < 3; ++p)
        pair_body(std::integral_constant<bool, false>{}, 2 * p + 1, 6, 2 * p + 2, 6);

    // -------- offset (0,0): d=0 -> w=1
#pragma unroll
    for (int j = 0; j < 4; ++j) {
        PxU p; p.u = spx[PXB(rg + j, c)];
        accx[j] += (float)p.h[0][0];
        accy[j] += (float)p.h[0][1];
        accz[j] += (float)p.h[1][0];
        accw[j] += 1.f;
    }

    // -------- epilogue
#pragma unroll
    for (int j = 0; j < 4; ++j) {
        int po = ((Y0 + rg + j) * IMG + X0 + c) * 3;
        float rw = 1.f / accw[j];
        out[po + 0] = accx[j] * rw;
        out[po + 1] = accy[j] * rw;
        out[po + 2] = accz[j] * rw;
    }
}

// ---------------------------------------------------------------- launch
extern "C" void kernel_launch(void* const* d_in, const int* in_sizes, int n_in,
                              void* d_out, int out_size, void* d_ws, size_t ws_size,
                              hipStream_t stream) {
    const float* x = (const float*)d_in[0];
    float* out = (float*)d_out;
    float* scal = (float*)d_ws;                       // [0] = sigma accumulator
    int* hist = (int*)((char*)d_ws + 64);             // NREP x 3 x 4096 ints

    // zero scal (sigma accum) + histograms in one memset
    (void)hipMemsetAsync(d_ws, 0, 64 + NREP * 3 * NBINS * sizeof(int), stream);
    wavelet_hist<<<(HH_S * HH_S + 255) / 256, 256, 0, stream>>>(x, hist);
    sigma_scan<<<3, 1024, 0, stream>>>(hist, scal);
    dim3 grid(IMG / TW, IMG / TH);
    nlm_main<<<grid, 512, 0, stream>>>(x, scal, out);
}

// Round 13
// 228.913 us; speedup vs baseline: 1.2638x; 1.0159x over previous
//
#include <hip/hip_runtime.h>
#include <hip/hip_fp16.h>
#include <math.h>
#include <type_traits>

// ----------------------------------------------------------------------------
// NL-means denoise (skimage slow-mode math) + db2-wavelet sigma estimate.
// Stage 1: wavelet HH conv (stride-2 SAMPLED grid) -> hist (2 replicas)
// Stage 2: 3 blocks (one per channel) shfl-scan -> median -> atomicAdd sigsum
// Stage 3: tiled NLM with +/- offset symmetry (R10: 42 iters cover 168 offs):
//     A: diff^2 (packed 2 offsets) on 42x80 ext  -> sds
//     B: horiz 5-tap (packed, /3 folded)         -> shh
//     W: vert 5-tap + exp2 weights on 38x76 ext  -> swt (b64 col-pair tasks)
//     C: gather swt[p], swt[p-o1], swt[p-o2] + 4 px reads, accumulate 4 dirs
// R13: swt is its OWN buffer (was aliasing sds) -> the end-of-iteration
//     barrier protecting sw from next-A writes is gone (4->3 barriers/iter)
//     and phase C overlaps per-thread with next iteration's phase A.
//     R12 post-mortem: W b64 gained only 2.6us -> wall is ~25% barrier
//     rendezvous, not LDS issue; this attacks that directly. LDS 62->73.4KB,
//     still 2 blocks/CU.
// ----------------------------------------------------------------------------

#define IMG   1024
#define HH_S  257
#define NBINS 4096
#define NREP  2
#define BIN_SCALE 4096.0f
#define MED_K 33025      // n=257*257=66049 odd: median = a[33024] (0-based)

#define TW 64
#define TH 32
// spx: rows -8..39 (48) x cols -14..77 (92)
#define PROWS 48
#define PCOLS 92
#define NPIX (PROWS*PCOLS)           // 4416
#define PXB(r,c) (((r)+8)*PCOLS + ((c)+14))
// sd: rows -8..33 (42) x cols -8..71 (80)
#define DCOLS 80
#define ND 3360                      // 42*80
// sh: rows -8..33 (42) x cols -6..69 (76)
#define HCOLS 76
#define NH 3192                      // 42*76
// swt: rows -6..31 (38) x cols -6..69 (76) — separate buffer (R13)
#define NW 2888                      // 38*76
#define NWP 1444                     // 38 rows x 38 col-pairs
#define SWB(r,c) (((r)+6)*HCOLS + ((c)+6))

// Gaussian patch kernel, normalized separable taps
#define G0 0.05448868454910367f
#define G1 0.24420134203151178f
#define G2 0.40261994689466440f
// horizontal pass taps pre-multiplied by 1/3 (channel mean)
#define B0 0.01816289484970122f
#define B1 0.08140044734383726f
#define B2 0.13420664896488813f

#define MAD_INV 1.4826022185056018f
#define LOG2E   1.4426950408889634f

typedef _Float16 half2v __attribute__((ext_vector_type(2)));
union PxU { uint2 u; half2v h[2]; };
union Q4  { uint4 u; half2v h[4]; };
union Q2  { uint2 u; half2v h[2]; };
#define H2(x) half2v{(_Float16)(x), (_Float16)(x)}

// ---------------------------------------------------------------- stage 1
__global__ void wavelet_hist(const float* __restrict__ x, int* __restrict__ hist) {
    int idx = blockIdx.x * 256 + threadIdx.x;
    if (idx >= HH_S * HH_S) return;
    int* hrep = hist + (blockIdx.x & (NREP - 1)) * 3 * NBINS;
    int i = (idx / HH_S) * 2;
    int j = (idx - (idx / HH_S) * HH_S) * 2;
    const float k4[4] = {-0.48296291314469025f, 0.8365163037378079f,
                         -0.2241438680420134f, -0.12940952255126037f};
    float acc0 = 0.f, acc1 = 0.f, acc2 = 0.f;
    const bool fast = (j >= 2 && j <= 511);
#pragma unroll
    for (int a = 0; a < 4; ++a) {
        int sy = 2 * i + a - 3;                       // 'symmetric' pad
        sy = sy < 0 ? -sy - 1 : (sy >= IMG ? 2 * IMG - 1 - sy : sy);
        const float* row = x + (size_t)sy * IMG * 3;
        float r0, r1, r2;
        if (fast) {
            const float* p = row + (2 * j - 3) * 3;
            float f0 = p[0], f1 = p[1], f2 = p[2], f3 = p[3];
            float f4 = p[4], f5 = p[5], f6 = p[6], f7 = p[7];
            float f8 = p[8], f9 = p[9], f10 = p[10], f11 = p[11];
            r0 = k4[0] * f0 + k4[1] * f3 + k4[2] * f6 + k4[3] * f9;
            r1 = k4[0] * f1 + k4[1] * f4 + k4[2] * f7 + k4[3] * f10;
            r2 = k4[0] * f2 + k4[1] * f5 + k4[2] * f8 + k4[3] * f11;
        } else {
            r0 = r1 = r2 = 0.f;
#pragma unroll
            for (int b = 0; b < 4; ++b) {
                int sx = 2 * j + b - 3;
                sx = sx < 0 ? -sx - 1 : (sx >= IMG ? 2 * IMG - 1 - sx : sx);
                const float* p = row + sx * 3;
                r0 += k4[b] * p[0]; r1 += k4[b] * p[1]; r2 += k4[b] * p[2];
            }
        }
        acc0 += k4[a] * r0; acc1 += k4[a] * r1; acc2 += k4[a] * r2;
    }
    int b0 = (int)(fabsf(acc0) * BIN_SCALE); b0 = b0 > NBINS - 1 ? NBINS - 1 : b0;
    int b1 = (int)(fabsf(acc1) * BIN_SCALE); b1 = b1 > NBINS - 1 ? NBINS - 1 : b1;
    int b2 = (int)(fabsf(acc2) * BIN_SCALE); b2 = b2 > NBINS - 1 ? NBINS - 1 : b2;
    atomicAdd(&hrep[b0], 1);
    atomicAdd(&hrep[NBINS + b1], 1);
    atomicAdd(&hrep[2 * NBINS + b2], 1);
}

// ---------------------------------------------------------------- stage 2
// one block per channel; accumulates med*MAD_INV/3 into scal[0] (pre-zeroed)
__global__ void sigma_scan(const int* __restrict__ hist, float* __restrict__ scal) {
    __shared__ int   wsum[16];
    __shared__ float sres[1];
    const int t = threadIdx.x;
    const int lane = t & 63, wid = t >> 6;
    const int c = blockIdx.x;
    const int* h = hist + c * NBINS;
    int cnt[4]; int tsum = 0;
#pragma unroll
    for (int b = 0; b < 4; ++b) {
        int bin = t * 4 + b, s = 0;
#pragma unroll
        for (int r = 0; r < NREP; ++r) s += h[r * 3 * NBINS + bin];
        cnt[b] = s; tsum += s;
    }
    int incl = tsum;
#pragma unroll
    for (int o = 1; o < 64; o <<= 1) {
        int v = __shfl_up(incl, o);
        if (lane >= o) incl += v;
    }
    if (lane == 63) wsum[wid] = incl;
    __syncthreads();
    if (wid == 0) {
        int v = (lane < 16) ? wsum[lane] : 0;
        int inc = v;
#pragma unroll
        for (int o = 1; o < 16; o <<= 1) {
            int u = __shfl_up(inc, o);
            if (lane >= o) inc += u;
        }
        if (lane < 16) wsum[lane] = inc - v;
    }
    __syncthreads();
    int cum = wsum[wid] + incl - tsum;
#pragma unroll
    for (int b = 0; b < 4; ++b) {
        int nc = cum + cnt[b];
        float v = (t * 4 + b + 0.5f) * (1.0f / BIN_SCALE);
        if (cum < MED_K && nc >= MED_K) sres[0] = v;
        cum = nc;
    }
    __syncthreads();
    if (t == 0) atomicAdd(&scal[0], sres[0] * (MAD_INV / 3.0f));
}

// ---------------------------------------------------------------- stage 3
__device__ __forceinline__ float diff2(half2v a01, half2v a2, half2v b01, half2v b2) {
#if __has_builtin(__builtin_amdgcn_fdot2)
    half2v e01 = a01 - b01;
    half2v e2  = a2  - b2;
    return __builtin_amdgcn_fdot2(e01, e01,
           __builtin_amdgcn_fdot2(e2, e2, 0.f, false), false);
#else
    float e0 = (float)a01[0] - (float)b01[0];
    float e1 = (float)a01[1] - (float)b01[1];
    float e2 = (float)a2[0]  - (float)b2[0];
    return e0 * e0 + e1 * e1 + e2 * e2;
#endif
}

__device__ __forceinline__ half2v pack2(float a, float b) {
#if __has_builtin(__builtin_amdgcn_cvt_pkrtz)
    return __builtin_bit_cast(half2v, __builtin_amdgcn_cvt_pkrtz(a, b));
#else
    return half2v{(_Float16)a, (_Float16)b};
#endif
}

__launch_bounds__(512, 4)
__global__ void nlm_main(const float* __restrict__ x,
                         const float* __restrict__ scal,
                         float* __restrict__ out) {
    __shared__ __align__(16) uint2  spx[NPIX];   // packed half RGB (RO in loop)
    __shared__ __align__(16) half2v sds[ND];     // diff^2 pairs
    __shared__ __align__(16) half2v shh[NH];     // horiz-conv pairs
    __shared__ __align__(16) half2v swt[NW];     // weight pairs (R13: own buf)

    const int tid = threadIdx.x;
    const int X0 = blockIdx.x * TW;
    const int Y0 = blockIdx.y * TH;

    // --- load reflect-padded pixel tile, pack RGB -> 3xfp16 in uint2
    for (int l = tid; l < NPIX; l += 512) {
        int rr = l / PCOLS;
        int cc = l - rr * PCOLS;
        int sy = Y0 + rr - 8;
        sy = sy < 0 ? -sy : (sy >= IMG ? 2 * IMG - 2 - sy : sy);
        int sc = X0 + cc - 14;
        sc = sc < 0 ? -sc : (sc >= IMG ? 2 * IMG - 2 - sc : sc);
        const float* p = x + ((size_t)sy * IMG + sc) * 3;
        uint2 u;
        u.x = (unsigned)__half_as_ushort(__float2half_rn(p[0])) |
              ((unsigned)__half_as_ushort(__float2half_rn(p[1])) << 16);
        u.y = (unsigned)__half_as_ushort(__float2half_rn(p[2]));  // hi 16 = 0
        spx[l] = u;
    }

    const float sigma = scal[0];
    const float var   = 2.0f * sigma * sigma;
    const float ih2l  = LOG2E / (0.64f * sigma * sigma);   // h = 0.8*sigma

    const int c  = tid & 63;          // output col within tile
    const int rg = (tid >> 6) * 4;    // first of 4 output rows (0..28)
    float accx[4] = {0, 0, 0, 0}, accy[4] = {0, 0, 0, 0};
    float accz[4] = {0, 0, 0, 0}, accw[4] = {0, 0, 0, 0};

    __syncthreads();

    // --- register-cache center values + spx base index for phase A tasks
    half2v ctr01[7], ctr2[7];
    int    pb[7];
#pragma unroll
    for (int k = 0; k < 7; ++k) {
        int i = (k < 6 || tid < ND - 6 * 512) ? tid + k * 512 : 0;
        int dr = i / DCOLS;
        int dc = i - dr * DCOLS;
        pb[k] = dr * PCOLS + dc + 6;   // PXB(dr-8, dc-8)
        PxU p; p.u = spx[pb[k]];
        ctr01[k] = p.h[0]; ctr2[k] = p.h[1];
    }

    const half2v B0h = H2(B0), B1h = H2(B1), B2h = H2(B2);
    const half2v G0h = H2(G0), G1h = H2(G1), G2h = H2(G2);

    // ---- pair body: offsets o1=(oy1,ox1), o2=(oy2,ox2) packed as half2;
    // each serves BOTH +o and -o directions (dist_{-o}(p) = dist_o(p-o)).
    // Barrier safety without the old end-of-iter barrier: next W writes swt
    // only after next post-B barrier, which every thread reaches only after
    // finishing its C (program order C_i -> A_{i+1} -> bar -> B -> bar -> W).
    auto pair_body = [&](auto mtag, int oy1, int ox1, int oy2, int ox2) {
        constexpr bool MERGED = decltype(mtag)::value;
        const int d1off = oy1 * PCOLS + ox1;
        const int d2off = oy2 * PCOLS + ox2;

        // -------- phase A: packed diff^2 on 42x80 ext region -> sds
#pragma unroll
        for (int k = 0; k < 7; ++k) {
            if (k < 6 || tid < ND - 6 * 512) {
                PxU p1, p2;
                p1.u = spx[pb[k] + d1off];
                if constexpr (MERGED) p2.u = spx[pb[k] + d1off + 1];
                else                  p2.u = spx[pb[k] + d2off];
                float da = diff2(ctr01[k], ctr2[k], p1.h[0], p1.h[1]);
                float db = diff2(ctr01[k], ctr2[k], p2.h[0], p2.h[1]);
                sds[tid + k * 512] = pack2(da, db);
            }
        }
        __syncthreads();

        // -------- phase B: packed horizontal conv -> shh (798 b128 tasks)
        {
            int row = tid / 19, g = tid - row * 19;
            int b = row * DCOLS + 4 * g;
            Q4 a, q, o;
            a.u = *(const uint4*)&sds[b];
            q.u = *(const uint4*)&sds[b + 4];
            o.h[0] = B0h * a.h[0] + B1h * a.h[1] + B2h * a.h[2] + B1h * a.h[3] + B0h * q.h[0];
            o.h[1] = B0h * a.h[1] + B1h * a.h[2] + B2h * a.h[3] + B1h * q.h[0] + B0h * q.h[1];
            o.h[2] = B0h * a.h[2] + B1h * a.h[3] + B2h * q.h[0] + B1h * q.h[1] + B0h * q.h[2];
            o.h[3] = B0h * a.h[3] + B1h * q.h[0] + B2h * q.h[1] + B1h * q.h[2] + B0h * q.h[3];
            *(uint4*)&shh[row * HCOLS + 4 * g] = o.u;
            if (tid < 798 - 512) {
                int j2 = tid + 512;
                int row2 = j2 / 19, g2 = j2 - row2 * 19;
                int b2 = row2 * DCOLS + 4 * g2;
                a.u = *(const uint4*)&sds[b2];
                q.u = *(const uint4*)&sds[b2 + 4];
                o.h[0] = B0h * a.h[0] + B1h * a.h[1] + B2h * a.h[2] + B1h * a.h[3] + B0h * q.h[0];
                o.h[1] = B0h * a.h[1] + B1h * a.h[2] + B2h * a.h[3] + B1h * q.h[0] + B0h * q.h[1];
                o.h[2] = B0h * a.h[2] + B1h * a.h[3] + B2h * q.h[0] + B1h * q.h[1] + B0h * q.h[2];
                o.h[3] = B0h * a.h[3] + B1h * q.h[0] + B2h * q.h[1] + B1h * q.h[2] + B0h * q.h[3];
                *(uint4*)&shh[row2 * HCOLS + 4 * g2] = o.u;
            }
        }
        __syncthreads();

        // -------- phase W: vert conv + exp2 weights, column-pair b64 tasks
#pragma unroll
        for (int k = 0; k < 3; ++k) {
            int t = tid + k * 512;
            if (k < 2 || t < NWP) {
                int row = t / 38, cp = t - row * 38;
                int m = row * HCOLS + 2 * cp;
                Q2 s0, s1, s2, s3, s4, o;
                s0.u = *(const uint2*)&shh[m];
                s1.u = *(const uint2*)&shh[m + HCOLS];
                s2.u = *(const uint2*)&shh[m + 2 * HCOLS];
                s3.u = *(const uint2*)&shh[m + 3 * HCOLS];
                s4.u = *(const uint2*)&shh[m + 4 * HCOLS];
                half2v d0 = G0h * s0.h[0] + G1h * s1.h[0] + G2h * s2.h[0] + G1h * s3.h[0] + G0h * s4.h[0];
                half2v d1 = G0h * s0.h[1] + G1h * s1.h[1] + G2h * s2.h[1] + G1h * s3.h[1] + G0h * s4.h[1];
                o.h[0] = pack2(exp2f(fminf(var - (float)d0[0], 0.f) * ih2l),
                               exp2f(fminf(var - (float)d0[1], 0.f) * ih2l));
                o.h[1] = pack2(exp2f(fminf(var - (float)d1[0], 0.f) * ih2l),
                               exp2f(fminf(var - (float)d1[1], 0.f) * ih2l));
                *(uint2*)&swt[m] = o.u;
            }
        }
        __syncthreads();

        // -------- phase C: accumulate 4 directions per packed pair
        // (overlaps with next iteration's phase A — no trailing barrier)
#pragma unroll
        for (int j = 0; j < 4; ++j) {
            int r = rg + j;
            half2v wp = swt[SWB(r, c)];
            _Float16 wm1h, wm2h;
            PxU pa, pbx, pm1, pm2;
            if constexpr (MERGED) {
                int wmb = SWB(r - oy1, c - ox1);
                wm1h = swt[wmb][0];
                wm2h = swt[wmb - 1][1];
                int ab = PXB(r + oy1, c + ox1);
                pa.u  = spx[ab]; pbx.u = spx[ab + 1];
                int mb = PXB(r - oy1, c - ox1);
                pm1.u = spx[mb]; pm2.u = spx[mb - 1];
            } else {
                wm1h  = swt[SWB(r - oy1, c - ox1)][0];
                wm2h  = swt[SWB(r - oy2, c - ox2)][1];
                pa.u  = spx[PXB(r + oy1, c + ox1)];
                pbx.u = spx[PXB(r + oy2, c + ox2)];
                pm1.u = spx[PXB(r - oy1, c - ox1)];
                pm2.u = spx[PXB(r - oy2, c - ox2)];
            }
            float w1 = (float)wp[0], w2 = (float)wp[1];
            float f1 = (float)wm1h, f2 = (float)wm2h;
            accx[j] += w1 * (float)pa.h[0][0] + w2 * (float)pbx.h[0][0]
                     + f1 * (float)pm1.h[0][0] + f2 * (float)pm2.h[0][0];
            accy[j] += w1 * (float)pa.h[0][1] + w2 * (float)pbx.h[0][1]
                     + f1 * (float)pm1.h[0][1] + f2 * (float)pm2.h[0][1];
            accz[j] += w1 * (float)pa.h[1][0] + w2 * (float)pbx.h[1][0]
                     + f1 * (float)pm1.h[1][0] + f2 * (float)pm2.h[1][0];
            accw[j] += (w1 + w2) + (f1 + f2);
        }
    };

    // ---- 42 iterations cover 84 representative offsets x 2 directions:
    // oy=0: ox 1..6 as merged pairs (1,2),(3,4),(5,6)
#pragma unroll 1
    for (int pi = 0; pi < 3; ++pi)
        pair_body(std::integral_constant<bool, true>{}, 0, 1 + 2 * pi, 0, 2 + 2 * pi);
    // oy=1..6: ox -6..5 as 6 merged pairs per row
#pragma unroll 1
    for (int oy = 1; oy <= 6; ++oy)
#pragma unroll 1
        for (int pi = 0; pi < 6; ++pi)
            pair_body(std::integral_constant<bool, true>{}, oy, -6 + 2 * pi, oy, -5 + 2 * pi);
    // leftovers (oy,6) for oy=1..6 as 3 generic pairs
#pragma unroll 1
    for (int p = 0; p < 3; ++p)
        pair_body(std::integral_constant<bool, false>{}, 2 * p + 1, 6, 2 * p + 2, 6);

    // -------- offset (0,0): d=0 -> w=1
#pragma unroll
    for (int j = 0; j < 4; ++j) {
        PxU p; p.u = spx[PXB(rg + j, c)];
        accx[j] += (float)p.h[0][0];
        accy[j] += (float)p.h[0][1];
        accz[j] += (float)p.h[1][0];
        accw[j] += 1.f;
    }

    // -------- epilogue
#pragma unroll
    for (int j = 0; j < 4; ++j) {
        int po = ((Y0 + rg + j) * IMG + X0 + c) * 3;
        float rw = 1.f / accw[j];
        out[po + 0] = accx[j] * rw;
        out[po + 1] = accy[j] * rw;
        out[po + 2] = accz[j] * rw;
    }
}

// ---------------------------------------------------------------- launch
extern "C" void kernel_launch(void* const* d_in, const int* in_sizes, int n_in,
                              void* d_out, int out_size, void* d_ws, size_t ws_size,
                              hipStream_t stream) {
    const float* x = (const float*)d_in[0];
    float* out = (float*)d_out;
    float* scal = (float*)d_ws;                       // [0] = sigma accumulator
    int* hist = (int*)((char*)d_ws + 64);             // NREP x 3 x 4096 ints

    // zero scal (sigma accum) + histograms in one memset
    (void)hipMemsetAsync(d_ws, 0, 64 + NREP * 3 * NBINS * sizeof(int), stream);
    wavelet_hist<<<(HH_S * HH_S + 255) / 256, 256, 0, stream>>>(x, hist);
    sigma_scan<<<3, 1024, 0, stream>>>(hist, scal);
    dim3 grid(IMG / TW, IMG / TH);
    nlm_main<<<grid, 512, 0, stream>>>(x, scal, out);
}